// Round 5
// baseline (1254.852 us; speedup 1.0000x reference)
//
#include <hip/hip_runtime.h>
#include <hip/hip_bf16.h>

#define N_NODES 200000
#define N_EDGES 800000
#define N_MOL   10000
#define HDIM    64
#define EDGE_DIM 16
#define BN_EPS 1e-5f

typedef __attribute__((ext_vector_type(8))) short short8;
typedef __attribute__((ext_vector_type(4))) float f32x4;

// ---------------------------------------------------------------------------
// bf16 helpers
// ---------------------------------------------------------------------------
__device__ __forceinline__ unsigned int pk2(float a, float b) {
    __hip_bfloat162 h = __float22bfloat162_rn(make_float2(a, b));
    union { __hip_bfloat162 h; unsigned int u; } c;
    c.h = h;
    return c.u;
}
__device__ __forceinline__ short8 cvt8(float4 a, float4 b) {
    union { short8 s; unsigned int u[4]; } r;
    r.u[0] = pk2(a.x, a.y); r.u[1] = pk2(a.z, a.w);
    r.u[2] = pk2(b.x, b.y); r.u[3] = pk2(b.z, b.w);
    return r.s;
}
__device__ __forceinline__ float4 add4(float4 a, float4 b) {
    return make_float4(a.x + b.x, a.y + b.y, a.z + b.z, a.w + b.w);
}

// ---------------------------------------------------------------------------
// CSR build: histogram -> single-block scan -> scatter (runs once per launch)
// ---------------------------------------------------------------------------
__global__ __launch_bounds__(256) void hist_kernel(
    const int* __restrict__ ei, int* __restrict__ counts)
{
    int e = blockIdx.x * 256 + threadIdx.x;
    if (e < N_EDGES) atomicAdd(&counts[ei[N_EDGES + e]], 1);
}

__global__ __launch_bounds__(1024) void scan_kernel(
    const int* __restrict__ counts,
    int* __restrict__ row_ptr, int* __restrict__ cursor)
{
    __shared__ int lds[1024];
    int t = threadIdx.x;
    const int CH = (N_NODES + 1023) / 1024;   // 196
    int lo = t * CH;
    int hi = min(lo + CH, N_NODES);
    int s = 0;
    for (int i = lo; i < hi; i++) s += counts[i];
    lds[t] = s;
    __syncthreads();
    // inclusive Hillis-Steele scan
    for (int off = 1; off < 1024; off <<= 1) {
        int v = (t >= off) ? lds[t - off] : 0;
        __syncthreads();
        lds[t] += v;
        __syncthreads();
    }
    int run = (t == 0) ? 0 : lds[t - 1];      // exclusive base
    for (int i = lo; i < hi; i++) {
        row_ptr[i] = run;
        cursor[i] = run;
        run += counts[i];
    }
    if (t == 1023) row_ptr[N_NODES] = run;    // last thread's base == grand total
}

__global__ __launch_bounds__(256) void scatter_kernel(
    const int* __restrict__ ei, int* __restrict__ cursor,
    int* __restrict__ src_sorted, int* __restrict__ eid_sorted)
{
    int e = blockIdx.x * 256 + threadIdx.x;
    if (e >= N_EDGES) return;
    int d = ei[N_EDGES + e];
    int pos = atomicAdd(&cursor[d], 1);
    src_sorted[pos] = ei[e];
    eid_sorted[pos] = e;
}

// ---------------------------------------------------------------------------
// Gather-aggregate (no atomics): wave owns 8 consecutive dst nodes, walks its
// CSR segment in chunks of 4 edges; msg = relu(x[src] + ea@We.T + be) summed
// in registers, agg row written once per node (coalesced, 256B).
// ---------------------------------------------------------------------------
template<int DIN>
__global__ __launch_bounds__(256) void agg_kernel(
    const float* __restrict__ xin, int stride_in,
    const int*   __restrict__ row_ptr,
    const int*   __restrict__ src_sorted,
    const int*   __restrict__ eid_sorted,
    const float* __restrict__ ea,
    const float* __restrict__ We,     // [DIN, 16]
    const float* __restrict__ be,     // [DIN]
    float*       __restrict__ agg)    // [N, 64], fully written
{
    int lane = threadIdx.x & 63;
    int wave = blockIdx.x * 4 + (threadIdx.x >> 6);
    int n0 = wave * 8;
    if (n0 >= N_NODES) return;
    int f = lane;
    int g = lane >> 4;

    float4 wr0 = {0,0,0,0}, wr1 = {0,0,0,0}, wr2 = {0,0,0,0}, wr3 = {0,0,0,0};
    float bias = 0.f;
    if (f < DIN) {
        const float4* w4 = reinterpret_cast<const float4*>(We + f * 16);
        wr0 = w4[0]; wr1 = w4[1]; wr2 = w4[2]; wr3 = w4[3];
        bias = be[f];
    }

    int lo = row_ptr[n0];
    int hi = row_ptr[n0 + 8];
    int cur = 0;
    int nb = row_ptr[n0 + 1];
    float acc = 0.f;

    for (int j0 = lo; j0 < hi; j0 += 4) {
        // clamped prefetch of up to 4 edges (static indexing, rule #20)
        int s0, s1, s2, s3, e0, e1, e2, e3;
        {
            int j1 = min(j0 + 1, hi - 1);
            int j2 = min(j0 + 2, hi - 1);
            int j3 = min(j0 + 3, hi - 1);
            s0 = src_sorted[j0]; s1 = src_sorted[j1];
            s2 = src_sorted[j2]; s3 = src_sorted[j3];
            e0 = eid_sorted[j0]; e1 = eid_sorted[j1];
            e2 = eid_sorted[j2]; e3 = eid_sorted[j3];
        }
        // per-lane ea load: lane group g covers edge g of this chunk
        int eg = (g == 0) ? e0 : (g == 1) ? e1 : (g == 2) ? e2 : e3;
        float eav = ea[(size_t)eg * EDGE_DIM + (lane & 15)];
        // 4 independent x gathers
        float xv0 = 0.f, xv1 = 0.f, xv2 = 0.f, xv3 = 0.f;
        if (f < DIN) {
            xv0 = xin[(size_t)s0 * stride_in + f];
            xv1 = xin[(size_t)s1 * stride_in + f];
            xv2 = xin[(size_t)s2 * stride_in + f];
            xv3 = xin[(size_t)s3 * stride_in + f];
        }

#pragma unroll
        for (int k = 0; k < 4; k++) {
            int j = j0 + k;
            if (j >= hi) break;                     // wave-uniform
            while (j >= nb) {                       // flush node boundary
                agg[(size_t)(n0 + cur) * HDIM + f] = acc;
                acc = 0.f;
                cur++;
                nb = row_ptr[n0 + cur + 1];
            }
            float ej[16];
#pragma unroll
            for (int jj = 0; jj < 16; jj++) ej[jj] = __shfl(eav, k * 16 + jj, 64);
            float xk = (k == 0) ? xv0 : (k == 1) ? xv1 : (k == 2) ? xv2 : xv3;
            if (f < DIN) {
                float a = bias;
                a += wr0.x * ej[0]  + wr0.y * ej[1]  + wr0.z * ej[2]  + wr0.w * ej[3];
                a += wr1.x * ej[4]  + wr1.y * ej[5]  + wr1.z * ej[6]  + wr1.w * ej[7];
                a += wr2.x * ej[8]  + wr2.y * ej[9]  + wr2.z * ej[10] + wr2.w * ej[11];
                a += wr3.x * ej[12] + wr3.y * ej[13] + wr3.z * ej[14] + wr3.w * ej[15];
                acc += fmaxf(xk + a, 0.f);
            }
        }
    }
    // flush remaining nodes (including trailing empty ones)
    while (cur < 8) {
        agg[(size_t)(n0 + cur) * HDIM + f] = acc;
        acc = 0.f;
        cur++;
    }
}

// ---------------------------------------------------------------------------
// Node MFMA kernel: h = leaky_relu(BN((x + agg) @ W.T + b))
// ---------------------------------------------------------------------------
template<int DIN>
__global__ __launch_bounds__(256) void node_mfma(
    const float* __restrict__ xin,    // [N, DIN]
    const float* __restrict__ agg,    // [N, 64] (cols 0..DIN-1 valid)
    float*       __restrict__ Bout,   // [N, 64]
    const float* __restrict__ W,      // [64, DIN]
    const float* __restrict__ bias,
    const float* __restrict__ gam,
    const float* __restrict__ bet,
    const float* __restrict__ mean,
    const float* __restrict__ var)
{
    int lane = threadIdx.x & 63;
    int wave = blockIdx.x * 4 + (threadIdx.x >> 6);
    if (wave >= N_NODES / 64) return;
    int n0 = wave * 64;
    int r = lane & 15;
    int g = lane >> 4;

    const short8 zero8 = (short8){0, 0, 0, 0, 0, 0, 0, 0};

    short8 zf[4][2];
#pragma unroll
    for (int nt = 0; nt < 4; nt++) {
        int node = n0 + nt * 16 + r;
        const float* xr = xin + (size_t)node * DIN;
        const float* ar = agg + (size_t)node * HDIM;
        float4 x0 = *(const float4*)(xr + g * 8);
        float4 x1 = *(const float4*)(xr + g * 8 + 4);
        float4 a0 = *(const float4*)(ar + g * 8);
        float4 a1 = *(const float4*)(ar + g * 8 + 4);
        zf[nt][0] = cvt8(add4(x0, a0), add4(x1, a1));
        if (DIN == 64) {
            x0 = *(const float4*)(xr + 32 + g * 8);
            x1 = *(const float4*)(xr + 36 + g * 8);
            a0 = *(const float4*)(ar + 32 + g * 8);
            a1 = *(const float4*)(ar + 36 + g * 8);
            zf[nt][1] = cvt8(add4(x0, a0), add4(x1, a1));
        } else {
            if (g == 0) {
                x0 = *(const float4*)(xr + 32);
                x1 = *(const float4*)(xr + 36);
                a0 = *(const float4*)(ar + 32);
                a1 = *(const float4*)(ar + 36);
                zf[nt][1] = cvt8(add4(x0, a0), add4(x1, a1));
            } else {
                zf[nt][1] = zero8;
            }
        }
    }

    const float4* b4  = (const float4*)bias;
    const float4* g4  = (const float4*)gam;
    const float4* be4 = (const float4*)bet;
    const float4* m4  = (const float4*)mean;
    const float4* v4  = (const float4*)var;

#pragma unroll
    for (int ft = 0; ft < 4; ft++) {
        const float* wr = W + (size_t)(ft * 16 + r) * DIN;
        short8 af[2];
        {
            float4 w0 = *(const float4*)(wr + g * 8);
            float4 w1 = *(const float4*)(wr + g * 8 + 4);
            af[0] = cvt8(w0, w1);
            if (DIN == 64) {
                w0 = *(const float4*)(wr + 32 + g * 8);
                w1 = *(const float4*)(wr + 36 + g * 8);
                af[1] = cvt8(w0, w1);
            } else if (g == 0) {
                w0 = *(const float4*)(wr + 32);
                w1 = *(const float4*)(wr + 36);
                af[1] = cvt8(w0, w1);
            } else {
                af[1] = zero8;
            }
        }

        f32x4 acc[4];
#pragma unroll
        for (int nt = 0; nt < 4; nt++) acc[nt] = (f32x4){0.f, 0.f, 0.f, 0.f};

#pragma unroll
        for (int ks = 0; ks < 2; ks++) {
#pragma unroll
            for (int nt = 0; nt < 4; nt++) {
                acc[nt] = __builtin_amdgcn_mfma_f32_16x16x32_bf16(
                    af[ks], zf[nt][ks], acc[nt], 0, 0, 0);
            }
        }

        int idx = ft * 4 + g;
        float4 bb = b4[idx], gg = g4[idx], bt = be4[idx], mm = m4[idx], vv = v4[idx];
        float s0 = gg.x * rsqrtf(vv.x + BN_EPS);
        float s1 = gg.y * rsqrtf(vv.y + BN_EPS);
        float s2 = gg.z * rsqrtf(vv.z + BN_EPS);
        float s3 = gg.w * rsqrtf(vv.w + BN_EPS);
#pragma unroll
        for (int nt = 0; nt < 4; nt++) {
            int node = n0 + nt * 16 + r;
            float y0 = s0 * (acc[nt][0] + bb.x - mm.x) + bt.x;
            float y1 = s1 * (acc[nt][1] + bb.y - mm.y) + bt.y;
            float y2 = s2 * (acc[nt][2] + bb.z - mm.z) + bt.z;
            float y3 = s3 * (acc[nt][3] + bb.w - mm.w) + bt.w;
            y0 = (y0 > 0.f) ? y0 : 0.01f * y0;
            y1 = (y1 > 0.f) ? y1 : 0.01f * y1;
            y2 = (y2 > 0.f) ? y2 : 0.01f * y2;
            y3 = (y3 > 0.f) ? y3 : 0.01f * y3;
            *(float4*)(Bout + (size_t)node * HDIM + ft * 16 + g * 4) =
                make_float4(y0, y1, y2, y3);
        }
    }
}

// ---------------------------------------------------------------------------
// Pool kernel: hpool[batch[i]] += h3[i]
// ---------------------------------------------------------------------------
__global__ __launch_bounds__(256) void pool_kernel(
    const float* __restrict__ h3,
    const int*   __restrict__ batch,
    float*       __restrict__ hpool)
{
    int gid = blockIdx.x * 256 + threadIdx.x;
    if (gid >= N_NODES * HDIM) return;
    int i = gid >> 6, f = gid & 63;
    atomicAdd(&hpool[(size_t)batch[i] * HDIM + f], h3[gid]);
}

// ---------------------------------------------------------------------------
// Head: out[i] = Wl2 . leaky(Wl1 @ z_i + bl1) + bl2,  z_i = [h1|h2|h3|hpool[batch]]
// ---------------------------------------------------------------------------
__global__ __launch_bounds__(256) void head_kernel(
    const float* __restrict__ h1, const float* __restrict__ h2,
    const float* __restrict__ h3, const float* __restrict__ hpool,
    const int*   __restrict__ batch,
    const float* __restrict__ Wl1, const float* __restrict__ bl1,
    const float* __restrict__ Wl2, const float* __restrict__ bl2,
    float*       __restrict__ out)
{
    int lane = threadIdx.x & 63;
    int wave = blockIdx.x * 4 + (threadIdx.x >> 6);
    if (wave >= N_NODES / 64) return;
    int n0 = wave * 64;
    int r = lane & 15;
    int g = lane >> 4;

    short8 zf[4][8];
#pragma unroll
    for (int nt = 0; nt < 4; nt++) {
        int node = n0 + nt * 16 + r;
        const float* r1 = h1 + (size_t)node * 64;
        const float* r2 = h2 + (size_t)node * 64;
        const float* r3 = h3 + (size_t)node * 64;
        const float* rp = hpool + (size_t)batch[node] * 64;
        const float4* q;
        q = (const float4*)(r1 + g * 8);        zf[nt][0] = cvt8(q[0], q[1]);
        q = (const float4*)(r1 + 32 + g * 8);   zf[nt][1] = cvt8(q[0], q[1]);
        q = (const float4*)(r2 + g * 8);        zf[nt][2] = cvt8(q[0], q[1]);
        q = (const float4*)(r2 + 32 + g * 8);   zf[nt][3] = cvt8(q[0], q[1]);
        q = (const float4*)(r3 + g * 8);        zf[nt][4] = cvt8(q[0], q[1]);
        q = (const float4*)(r3 + 32 + g * 8);   zf[nt][5] = cvt8(q[0], q[1]);
        q = (const float4*)(rp + g * 8);        zf[nt][6] = cvt8(q[0], q[1]);
        q = (const float4*)(rp + 32 + g * 8);   zf[nt][7] = cvt8(q[0], q[1]);
    }

    float p[4] = {0.f, 0.f, 0.f, 0.f};

    const float4* bl1_4 = (const float4*)bl1;
    const float4* wl2_4 = (const float4*)Wl2;

#pragma unroll 1
    for (int ft = 0; ft < 16; ft++) {
        const float* arow = Wl1 + (size_t)(ft * 16 + r) * 256 + g * 8;
        short8 af[8];
#pragma unroll
        for (int ks = 0; ks < 8; ks++) {
            const float4* q = (const float4*)(arow + ks * 32);
            af[ks] = cvt8(q[0], q[1]);
        }

        f32x4 acc[4];
#pragma unroll
        for (int nt = 0; nt < 4; nt++) acc[nt] = (f32x4){0.f, 0.f, 0.f, 0.f};

#pragma unroll
        for (int ks = 0; ks < 8; ks++) {
#pragma unroll
            for (int nt = 0; nt < 4; nt++) {
                acc[nt] = __builtin_amdgcn_mfma_f32_16x16x32_bf16(
                    af[ks], zf[nt][ks], acc[nt], 0, 0, 0);
            }
        }

        float4 bl = bl1_4[ft * 4 + g];
        float4 w2 = wl2_4[ft * 4 + g];
#pragma unroll
        for (int nt = 0; nt < 4; nt++) {
            float a0 = acc[nt][0] + bl.x;
            float a1 = acc[nt][1] + bl.y;
            float a2 = acc[nt][2] + bl.z;
            float a3 = acc[nt][3] + bl.w;
            a0 = (a0 > 0.f) ? a0 : 0.01f * a0;
            a1 = (a1 > 0.f) ? a1 : 0.01f * a1;
            a2 = (a2 > 0.f) ? a2 : 0.01f * a2;
            a3 = (a3 > 0.f) ? a3 : 0.01f * a3;
            p[nt] += w2.x * a0 + w2.y * a1 + w2.z * a2 + w2.w * a3;
        }
    }

    float b2 = bl2[0];
#pragma unroll
    for (int nt = 0; nt < 4; nt++) {
        float s = p[nt];
        s += __shfl_xor(s, 16, 64);
        s += __shfl_xor(s, 32, 64);
        if (g == 0) out[n0 + nt * 16 + r] = s + b2;
    }
}

// ---------------------------------------------------------------------------
extern "C" void kernel_launch(void* const* d_in, const int* in_sizes, int n_in,
                              void* d_out, int out_size, void* d_ws, size_t ws_size,
                              hipStream_t stream) {
    const float* x     = (const float*)d_in[0];
    const int*   ei    = (const int*)  d_in[1];
    const float* ea    = (const float*)d_in[2];
    const int*   batch = (const int*)  d_in[3];

    const float* We1 = (const float*)d_in[4];  const float* be1 = (const float*)d_in[5];
    const float* W1  = (const float*)d_in[6];  const float* b1  = (const float*)d_in[7];
    const float* g1  = (const float*)d_in[8];  const float* bb1 = (const float*)d_in[9];
    const float* m1  = (const float*)d_in[10]; const float* v1  = (const float*)d_in[11];

    const float* We2 = (const float*)d_in[12]; const float* be2 = (const float*)d_in[13];
    const float* W2  = (const float*)d_in[14]; const float* b2  = (const float*)d_in[15];
    const float* g2  = (const float*)d_in[16]; const float* bb2 = (const float*)d_in[17];
    const float* m2  = (const float*)d_in[18]; const float* v2  = (const float*)d_in[19];

    const float* We3 = (const float*)d_in[20]; const float* be3 = (const float*)d_in[21];
    const float* W3  = (const float*)d_in[22]; const float* b3  = (const float*)d_in[23];
    const float* g3  = (const float*)d_in[24]; const float* bb3 = (const float*)d_in[25];
    const float* m3  = (const float*)d_in[26]; const float* v3  = (const float*)d_in[27];

    const float* Wl1 = (const float*)d_in[28]; const float* bl1 = (const float*)d_in[29];
    const float* Wl2 = (const float*)d_in[30]; const float* bl2 = (const float*)d_in[31];

    float* out = (float*)d_out;

    // ---- workspace layout ----
    float* B1    = (float*)d_ws;                  // [N,64] agg1 -> h1
    float* B2    = B1 + (size_t)N_NODES * HDIM;   // [N,64]
    float* B3    = B2 + (size_t)N_NODES * HDIM;   // [N,64]
    float* hpool = B3 + (size_t)N_NODES * HDIM;   // [N_MOL,64]
    int* counts     = (int*)(hpool + (size_t)N_MOL * HDIM);   // [N]
    int* row_ptr    = counts + N_NODES;                       // [N+1]
    int* cursor     = row_ptr + N_NODES + 1;                  // [N]
    int* src_sorted = cursor + N_NODES;                       // [E]
    int* eid_sorted = src_sorted + N_EDGES;                   // [E]

    // zero hpool + counts
    hipMemsetAsync(hpool, 0, (size_t)N_MOL * HDIM * sizeof(float), stream);
    hipMemsetAsync(counts, 0, (size_t)N_NODES * sizeof(int), stream);

    dim3 blk(256);
    dim3 egrid(N_EDGES / 256);                 // 3125
    dim3 agrid((N_NODES / 8) / 4);             // 6250 (25000 waves, 8 nodes each)
    dim3 ngrid((N_NODES / 64 + 3) / 4);
    dim3 pgrid((N_NODES * HDIM) / 256);
    dim3 hgrid((N_NODES / 64 + 3) / 4);

    // ---- CSR build (once) ----
    hist_kernel<<<egrid, blk, 0, stream>>>(ei, counts);
    scan_kernel<<<1, 1024, 0, stream>>>(counts, row_ptr, cursor);
    scatter_kernel<<<egrid, blk, 0, stream>>>(ei, cursor, src_sorted, eid_sorted);

    // layer 1
    agg_kernel<40><<<agrid, blk, 0, stream>>>(x, 40, row_ptr, src_sorted, eid_sorted,
                                              ea, We1, be1, B1);
    node_mfma<40><<<ngrid, blk, 0, stream>>>(x, B1, B1, W1, b1, g1, bb1, m1, v1);
    // layer 2
    agg_kernel<64><<<agrid, blk, 0, stream>>>(B1, 64, row_ptr, src_sorted, eid_sorted,
                                              ea, We2, be2, B2);
    node_mfma<64><<<ngrid, blk, 0, stream>>>(B1, B2, B2, W2, b2, g2, bb2, m2, v2);
    // layer 3
    agg_kernel<64><<<agrid, blk, 0, stream>>>(B2, 64, row_ptr, src_sorted, eid_sorted,
                                              ea, We3, be3, B3);
    node_mfma<64><<<ngrid, blk, 0, stream>>>(B2, B3, B3, W3, b3, g3, bb3, m3, v3);
    // pool
    pool_kernel<<<pgrid, blk, 0, stream>>>(B3, batch, hpool);
    // head (MFMA)
    head_kernel<<<hgrid, blk, 0, stream>>>(B1, B2, B3, hpool, batch,
                                           Wl1, bl1, Wl2, bl2, out);
}

// Round 6
// 816.367 us; speedup vs baseline: 1.5371x; 1.5371x over previous
//
#include <hip/hip_runtime.h>
#include <hip/hip_bf16.h>

#define N_NODES 200000
#define N_EDGES 800000
#define N_MOL   10000
#define HDIM    64
#define EDGE_DIM 16
#define BN_EPS 1e-5f
#define SCAN_BLOCKS ((N_NODES + 255) / 256)   // 782

typedef __attribute__((ext_vector_type(8))) short short8;
typedef __attribute__((ext_vector_type(4))) float f32x4;

// ---------------------------------------------------------------------------
// bf16 helpers
// ---------------------------------------------------------------------------
__device__ __forceinline__ unsigned int pk2(float a, float b) {
    __hip_bfloat162 h = __float22bfloat162_rn(make_float2(a, b));
    union { __hip_bfloat162 h; unsigned int u; } c;
    c.h = h;
    return c.u;
}
__device__ __forceinline__ short8 cvt8(float4 a, float4 b) {
    union { short8 s; unsigned int u[4]; } r;
    r.u[0] = pk2(a.x, a.y); r.u[1] = pk2(a.z, a.w);
    r.u[2] = pk2(b.x, b.y); r.u[3] = pk2(b.z, b.w);
    return r.s;
}
__device__ __forceinline__ float4 add4(float4 a, float4 b) {
    return make_float4(a.x + b.x, a.y + b.y, a.z + b.z, a.w + b.w);
}

// ---------------------------------------------------------------------------
// CSR build: histogram -> 3-phase parallel scan -> scatter
// ---------------------------------------------------------------------------
__global__ __launch_bounds__(256) void hist_kernel(
    const int* __restrict__ ei, int* __restrict__ counts)
{
    int e = blockIdx.x * 256 + threadIdx.x;
    if (e < N_EDGES) atomicAdd(&counts[ei[N_EDGES + e]], 1);
}

// Phase A: per-block inclusive scan; write local-EXCLUSIVE into row_ptr,
// block total into block_sums.
__global__ __launch_bounds__(256) void scan_phase_a(
    const int* __restrict__ counts,
    int* __restrict__ row_ptr,        // [N] local-exclusive (temp)
    int* __restrict__ block_sums)     // [SCAN_BLOCKS]
{
    __shared__ int lds[256];
    int t = threadIdx.x;
    int i = blockIdx.x * 256 + t;
    int v = (i < N_NODES) ? counts[i] : 0;
    lds[t] = v;
    __syncthreads();
    for (int off = 1; off < 256; off <<= 1) {
        int u = (t >= off) ? lds[t - off] : 0;
        __syncthreads();
        lds[t] += u;
        __syncthreads();
    }
    if (i < N_NODES) row_ptr[i] = lds[t] - v;
    if (t == 255) block_sums[blockIdx.x] = lds[255];
}

// Phase B: single block scans the 782 block sums -> exclusive, in place.
__global__ __launch_bounds__(1024) void scan_phase_b(
    int* __restrict__ block_sums)
{
    __shared__ int lds[1024];
    int t = threadIdx.x;
    int v = (t < SCAN_BLOCKS) ? block_sums[t] : 0;
    lds[t] = v;
    __syncthreads();
    for (int off = 1; off < 1024; off <<= 1) {
        int u = (t >= off) ? lds[t - off] : 0;
        __syncthreads();
        lds[t] += u;
        __syncthreads();
    }
    if (t < SCAN_BLOCKS) block_sums[t] = lds[t] - v;
}

// Phase C: add block base; fan out to row_ptr + cursor; row_ptr[N] = E.
__global__ __launch_bounds__(256) void scan_phase_c(
    const int* __restrict__ block_sums,
    int* __restrict__ row_ptr,
    int* __restrict__ cursor)
{
    int i = blockIdx.x * 256 + threadIdx.x;
    if (i < N_NODES) {
        int v = row_ptr[i] + block_sums[blockIdx.x];
        row_ptr[i] = v;
        cursor[i] = v;
    }
    if (i == 0) row_ptr[N_NODES] = N_EDGES;
}

__global__ __launch_bounds__(256) void scatter_kernel(
    const int* __restrict__ ei, int* __restrict__ cursor,
    int* __restrict__ src_sorted, int* __restrict__ eid_sorted)
{
    int e = blockIdx.x * 256 + threadIdx.x;
    if (e >= N_EDGES) return;
    int d = ei[N_EDGES + e];
    int pos = atomicAdd(&cursor[d], 1);
    src_sorted[pos] = ei[e];
    eid_sorted[pos] = e;
}

// ---------------------------------------------------------------------------
// Gather-aggregate (no atomics): wave owns 8 consecutive dst nodes, walks its
// CSR segment in chunks of 4 edges; msg = relu(x[src] + ea@We.T + be) summed
// in registers, agg row written once per node (coalesced, 256B).
// ---------------------------------------------------------------------------
template<int DIN>
__global__ __launch_bounds__(256) void agg_kernel(
    const float* __restrict__ xin, int stride_in,
    const int*   __restrict__ row_ptr,
    const int*   __restrict__ src_sorted,
    const int*   __restrict__ eid_sorted,
    const float* __restrict__ ea,
    const float* __restrict__ We,     // [DIN, 16]
    const float* __restrict__ be,     // [DIN]
    float*       __restrict__ agg)    // [N, 64], fully written
{
    int lane = threadIdx.x & 63;
    int wave = blockIdx.x * 4 + (threadIdx.x >> 6);
    int n0 = wave * 8;
    if (n0 >= N_NODES) return;
    int f = lane;
    int g = lane >> 4;

    float4 wr0 = {0,0,0,0}, wr1 = {0,0,0,0}, wr2 = {0,0,0,0}, wr3 = {0,0,0,0};
    float bias = 0.f;
    if (f < DIN) {
        const float4* w4 = reinterpret_cast<const float4*>(We + f * 16);
        wr0 = w4[0]; wr1 = w4[1]; wr2 = w4[2]; wr3 = w4[3];
        bias = be[f];
    }

    int lo = row_ptr[n0];
    int hi = row_ptr[n0 + 8];
    int cur = 0;
    int nb = row_ptr[n0 + 1];
    float acc = 0.f;

    for (int j0 = lo; j0 < hi; j0 += 4) {
        int s0, s1, s2, s3, e0, e1, e2, e3;
        {
            int j1 = min(j0 + 1, hi - 1);
            int j2 = min(j0 + 2, hi - 1);
            int j3 = min(j0 + 3, hi - 1);
            s0 = src_sorted[j0]; s1 = src_sorted[j1];
            s2 = src_sorted[j2]; s3 = src_sorted[j3];
            e0 = eid_sorted[j0]; e1 = eid_sorted[j1];
            e2 = eid_sorted[j2]; e3 = eid_sorted[j3];
        }
        int eg = (g == 0) ? e0 : (g == 1) ? e1 : (g == 2) ? e2 : e3;
        float eav = ea[(size_t)eg * EDGE_DIM + (lane & 15)];
        float xv0 = 0.f, xv1 = 0.f, xv2 = 0.f, xv3 = 0.f;
        if (f < DIN) {
            xv0 = xin[(size_t)s0 * stride_in + f];
            xv1 = xin[(size_t)s1 * stride_in + f];
            xv2 = xin[(size_t)s2 * stride_in + f];
            xv3 = xin[(size_t)s3 * stride_in + f];
        }

#pragma unroll
        for (int k = 0; k < 4; k++) {
            int j = j0 + k;
            if (j >= hi) break;                     // wave-uniform
            while (j >= nb) {                       // flush node boundary
                agg[(size_t)(n0 + cur) * HDIM + f] = acc;
                acc = 0.f;
                cur++;
                nb = row_ptr[n0 + cur + 1];
            }
            float ej[16];
#pragma unroll
            for (int jj = 0; jj < 16; jj++) ej[jj] = __shfl(eav, k * 16 + jj, 64);
            float xk = (k == 0) ? xv0 : (k == 1) ? xv1 : (k == 2) ? xv2 : xv3;
            if (f < DIN) {
                float a = bias;
                a += wr0.x * ej[0]  + wr0.y * ej[1]  + wr0.z * ej[2]  + wr0.w * ej[3];
                a += wr1.x * ej[4]  + wr1.y * ej[5]  + wr1.z * ej[6]  + wr1.w * ej[7];
                a += wr2.x * ej[8]  + wr2.y * ej[9]  + wr2.z * ej[10] + wr2.w * ej[11];
                a += wr3.x * ej[12] + wr3.y * ej[13] + wr3.z * ej[14] + wr3.w * ej[15];
                acc += fmaxf(xk + a, 0.f);
            }
        }
    }
    while (cur < 8) {
        agg[(size_t)(n0 + cur) * HDIM + f] = acc;
        acc = 0.f;
        cur++;
    }
}

// ---------------------------------------------------------------------------
// Node MFMA kernel: h = leaky_relu(BN((x + agg) @ W.T + b))
// ---------------------------------------------------------------------------
template<int DIN>
__global__ __launch_bounds__(256) void node_mfma(
    const float* __restrict__ xin,    // [N, DIN]
    const float* __restrict__ agg,    // [N, 64] (cols 0..DIN-1 valid)
    float*       __restrict__ Bout,   // [N, 64]
    const float* __restrict__ W,      // [64, DIN]
    const float* __restrict__ bias,
    const float* __restrict__ gam,
    const float* __restrict__ bet,
    const float* __restrict__ mean,
    const float* __restrict__ var)
{
    int lane = threadIdx.x & 63;
    int wave = blockIdx.x * 4 + (threadIdx.x >> 6);
    if (wave >= N_NODES / 64) return;
    int n0 = wave * 64;
    int r = lane & 15;
    int g = lane >> 4;

    const short8 zero8 = (short8){0, 0, 0, 0, 0, 0, 0, 0};

    short8 zf[4][2];
#pragma unroll
    for (int nt = 0; nt < 4; nt++) {
        int node = n0 + nt * 16 + r;
        const float* xr = xin + (size_t)node * DIN;
        const float* ar = agg + (size_t)node * HDIM;
        float4 x0 = *(const float4*)(xr + g * 8);
        float4 x1 = *(const float4*)(xr + g * 8 + 4);
        float4 a0 = *(const float4*)(ar + g * 8);
        float4 a1 = *(const float4*)(ar + g * 8 + 4);
        zf[nt][0] = cvt8(add4(x0, a0), add4(x1, a1));
        if (DIN == 64) {
            x0 = *(const float4*)(xr + 32 + g * 8);
            x1 = *(const float4*)(xr + 36 + g * 8);
            a0 = *(const float4*)(ar + 32 + g * 8);
            a1 = *(const float4*)(ar + 36 + g * 8);
            zf[nt][1] = cvt8(add4(x0, a0), add4(x1, a1));
        } else {
            if (g == 0) {
                x0 = *(const float4*)(xr + 32);
                x1 = *(const float4*)(xr + 36);
                a0 = *(const float4*)(ar + 32);
                a1 = *(const float4*)(ar + 36);
                zf[nt][1] = cvt8(add4(x0, a0), add4(x1, a1));
            } else {
                zf[nt][1] = zero8;
            }
        }
    }

    const float4* b4  = (const float4*)bias;
    const float4* g4  = (const float4*)gam;
    const float4* be4 = (const float4*)bet;
    const float4* m4  = (const float4*)mean;
    const float4* v4  = (const float4*)var;

#pragma unroll
    for (int ft = 0; ft < 4; ft++) {
        const float* wr = W + (size_t)(ft * 16 + r) * DIN;
        short8 af[2];
        {
            float4 w0 = *(const float4*)(wr + g * 8);
            float4 w1 = *(const float4*)(wr + g * 8 + 4);
            af[0] = cvt8(w0, w1);
            if (DIN == 64) {
                w0 = *(const float4*)(wr + 32 + g * 8);
                w1 = *(const float4*)(wr + 36 + g * 8);
                af[1] = cvt8(w0, w1);
            } else if (g == 0) {
                w0 = *(const float4*)(wr + 32);
                w1 = *(const float4*)(wr + 36);
                af[1] = cvt8(w0, w1);
            } else {
                af[1] = zero8;
            }
        }

        f32x4 acc[4];
#pragma unroll
        for (int nt = 0; nt < 4; nt++) acc[nt] = (f32x4){0.f, 0.f, 0.f, 0.f};

#pragma unroll
        for (int ks = 0; ks < 2; ks++) {
#pragma unroll
            for (int nt = 0; nt < 4; nt++) {
                acc[nt] = __builtin_amdgcn_mfma_f32_16x16x32_bf16(
                    af[ks], zf[nt][ks], acc[nt], 0, 0, 0);
            }
        }

        int idx = ft * 4 + g;
        float4 bb = b4[idx], gg = g4[idx], bt = be4[idx], mm = m4[idx], vv = v4[idx];
        float s0 = gg.x * rsqrtf(vv.x + BN_EPS);
        float s1 = gg.y * rsqrtf(vv.y + BN_EPS);
        float s2 = gg.z * rsqrtf(vv.z + BN_EPS);
        float s3 = gg.w * rsqrtf(vv.w + BN_EPS);
#pragma unroll
        for (int nt = 0; nt < 4; nt++) {
            int node = n0 + nt * 16 + r;
            float y0 = s0 * (acc[nt][0] + bb.x - mm.x) + bt.x;
            float y1 = s1 * (acc[nt][1] + bb.y - mm.y) + bt.y;
            float y2 = s2 * (acc[nt][2] + bb.z - mm.z) + bt.z;
            float y3 = s3 * (acc[nt][3] + bb.w - mm.w) + bt.w;
            y0 = (y0 > 0.f) ? y0 : 0.01f * y0;
            y1 = (y1 > 0.f) ? y1 : 0.01f * y1;
            y2 = (y2 > 0.f) ? y2 : 0.01f * y2;
            y3 = (y3 > 0.f) ? y3 : 0.01f * y3;
            *(float4*)(Bout + (size_t)node * HDIM + ft * 16 + g * 4) =
                make_float4(y0, y1, y2, y3);
        }
    }
}

// ---------------------------------------------------------------------------
// Pool kernel: hpool[batch[i]] += h3[i]
// ---------------------------------------------------------------------------
__global__ __launch_bounds__(256) void pool_kernel(
    const float* __restrict__ h3,
    const int*   __restrict__ batch,
    float*       __restrict__ hpool)
{
    int gid = blockIdx.x * 256 + threadIdx.x;
    if (gid >= N_NODES * HDIM) return;
    int i = gid >> 6, f = gid & 63;
    atomicAdd(&hpool[(size_t)batch[i] * HDIM + f], h3[gid]);
}

// ---------------------------------------------------------------------------
// Head: out[i] = Wl2 . leaky(Wl1 @ z_i + bl1) + bl2,  z_i = [h1|h2|h3|hpool[batch]]
// ---------------------------------------------------------------------------
__global__ __launch_bounds__(256) void head_kernel(
    const float* __restrict__ h1, const float* __restrict__ h2,
    const float* __restrict__ h3, const float* __restrict__ hpool,
    const int*   __restrict__ batch,
    const float* __restrict__ Wl1, const float* __restrict__ bl1,
    const float* __restrict__ Wl2, const float* __restrict__ bl2,
    float*       __restrict__ out)
{
    int lane = threadIdx.x & 63;
    int wave = blockIdx.x * 4 + (threadIdx.x >> 6);
    if (wave >= N_NODES / 64) return;
    int n0 = wave * 64;
    int r = lane & 15;
    int g = lane >> 4;

    short8 zf[4][8];
#pragma unroll
    for (int nt = 0; nt < 4; nt++) {
        int node = n0 + nt * 16 + r;
        const float* r1 = h1 + (size_t)node * 64;
        const float* r2 = h2 + (size_t)node * 64;
        const float* r3 = h3 + (size_t)node * 64;
        const float* rp = hpool + (size_t)batch[node] * 64;
        const float4* q;
        q = (const float4*)(r1 + g * 8);        zf[nt][0] = cvt8(q[0], q[1]);
        q = (const float4*)(r1 + 32 + g * 8);   zf[nt][1] = cvt8(q[0], q[1]);
        q = (const float4*)(r2 + g * 8);        zf[nt][2] = cvt8(q[0], q[1]);
        q = (const float4*)(r2 + 32 + g * 8);   zf[nt][3] = cvt8(q[0], q[1]);
        q = (const float4*)(r3 + g * 8);        zf[nt][4] = cvt8(q[0], q[1]);
        q = (const float4*)(r3 + 32 + g * 8);   zf[nt][5] = cvt8(q[0], q[1]);
        q = (const float4*)(rp + g * 8);        zf[nt][6] = cvt8(q[0], q[1]);
        q = (const float4*)(rp + 32 + g * 8);   zf[nt][7] = cvt8(q[0], q[1]);
    }

    float p[4] = {0.f, 0.f, 0.f, 0.f};

    const float4* bl1_4 = (const float4*)bl1;
    const float4* wl2_4 = (const float4*)Wl2;

#pragma unroll 1
    for (int ft = 0; ft < 16; ft++) {
        const float* arow = Wl1 + (size_t)(ft * 16 + r) * 256 + g * 8;
        short8 af[8];
#pragma unroll
        for (int ks = 0; ks < 8; ks++) {
            const float4* q = (const float4*)(arow + ks * 32);
            af[ks] = cvt8(q[0], q[1]);
        }

        f32x4 acc[4];
#pragma unroll
        for (int nt = 0; nt < 4; nt++) acc[nt] = (f32x4){0.f, 0.f, 0.f, 0.f};

#pragma unroll
        for (int ks = 0; ks < 8; ks++) {
#pragma unroll
            for (int nt = 0; nt < 4; nt++) {
                acc[nt] = __builtin_amdgcn_mfma_f32_16x16x32_bf16(
                    af[ks], zf[nt][ks], acc[nt], 0, 0, 0);
            }
        }

        float4 bl = bl1_4[ft * 4 + g];
        float4 w2 = wl2_4[ft * 4 + g];
#pragma unroll
        for (int nt = 0; nt < 4; nt++) {
            float a0 = acc[nt][0] + bl.x;
            float a1 = acc[nt][1] + bl.y;
            float a2 = acc[nt][2] + bl.z;
            float a3 = acc[nt][3] + bl.w;
            a0 = (a0 > 0.f) ? a0 : 0.01f * a0;
            a1 = (a1 > 0.f) ? a1 : 0.01f * a1;
            a2 = (a2 > 0.f) ? a2 : 0.01f * a2;
            a3 = (a3 > 0.f) ? a3 : 0.01f * a3;
            p[nt] += w2.x * a0 + w2.y * a1 + w2.z * a2 + w2.w * a3;
        }
    }

    float b2 = bl2[0];
#pragma unroll
    for (int nt = 0; nt < 4; nt++) {
        float s = p[nt];
        s += __shfl_xor(s, 16, 64);
        s += __shfl_xor(s, 32, 64);
        if (g == 0) out[n0 + nt * 16 + r] = s + b2;
    }
}

// ---------------------------------------------------------------------------
extern "C" void kernel_launch(void* const* d_in, const int* in_sizes, int n_in,
                              void* d_out, int out_size, void* d_ws, size_t ws_size,
                              hipStream_t stream) {
    const float* x     = (const float*)d_in[0];
    const int*   ei    = (const int*)  d_in[1];
    const float* ea    = (const float*)d_in[2];
    const int*   batch = (const int*)  d_in[3];

    const float* We1 = (const float*)d_in[4];  const float* be1 = (const float*)d_in[5];
    const float* W1  = (const float*)d_in[6];  const float* b1  = (const float*)d_in[7];
    const float* g1  = (const float*)d_in[8];  const float* bb1 = (const float*)d_in[9];
    const float* m1  = (const float*)d_in[10]; const float* v1  = (const float*)d_in[11];

    const float* We2 = (const float*)d_in[12]; const float* be2 = (const float*)d_in[13];
    const float* W2  = (const float*)d_in[14]; const float* b2  = (const float*)d_in[15];
    const float* g2  = (const float*)d_in[16]; const float* bb2 = (const float*)d_in[17];
    const float* m2  = (const float*)d_in[18]; const float* v2  = (const float*)d_in[19];

    const float* We3 = (const float*)d_in[20]; const float* be3 = (const float*)d_in[21];
    const float* W3  = (const float*)d_in[22]; const float* b3  = (const float*)d_in[23];
    const float* g3  = (const float*)d_in[24]; const float* bb3 = (const float*)d_in[25];
    const float* m3  = (const float*)d_in[26]; const float* v3  = (const float*)d_in[27];

    const float* Wl1 = (const float*)d_in[28]; const float* bl1 = (const float*)d_in[29];
    const float* Wl2 = (const float*)d_in[30]; const float* bl2 = (const float*)d_in[31];

    float* out = (float*)d_out;

    // ---- workspace layout ----
    float* B1    = (float*)d_ws;                  // [N,64] agg1 -> h1
    float* B2    = B1 + (size_t)N_NODES * HDIM;   // [N,64]
    float* B3    = B2 + (size_t)N_NODES * HDIM;   // [N,64]
    float* hpool = B3 + (size_t)N_NODES * HDIM;   // [N_MOL,64]
    int* counts     = (int*)(hpool + (size_t)N_MOL * HDIM);   // [N]
    int* row_ptr    = counts + N_NODES;                       // [N+1]
    int* cursor     = row_ptr + N_NODES + 1;                  // [N]
    int* src_sorted = cursor + N_NODES;                       // [E]
    int* eid_sorted = src_sorted + N_EDGES;                   // [E]
    int* block_sums = eid_sorted + N_EDGES;                   // [SCAN_BLOCKS]

    // zero hpool + counts
    hipMemsetAsync(hpool, 0, (size_t)N_MOL * HDIM * sizeof(float), stream);
    hipMemsetAsync(counts, 0, (size_t)N_NODES * sizeof(int), stream);

    dim3 blk(256);
    dim3 egrid(N_EDGES / 256);                 // 3125
    dim3 sgrid(SCAN_BLOCKS);                   // 782
    dim3 agrid((N_NODES / 8) / 4);             // 6250
    dim3 ngrid((N_NODES / 64 + 3) / 4);
    dim3 pgrid((N_NODES * HDIM) / 256);
    dim3 hgrid((N_NODES / 64 + 3) / 4);

    // ---- CSR build (once per launch) ----
    hist_kernel<<<egrid, blk, 0, stream>>>(ei, counts);
    scan_phase_a<<<sgrid, blk, 0, stream>>>(counts, row_ptr, block_sums);
    scan_phase_b<<<1, 1024, 0, stream>>>(block_sums);
    scan_phase_c<<<sgrid, blk, 0, stream>>>(block_sums, row_ptr, cursor);
    scatter_kernel<<<egrid, blk, 0, stream>>>(ei, cursor, src_sorted, eid_sorted);

    // layer 1
    agg_kernel<40><<<agrid, blk, 0, stream>>>(x, 40, row_ptr, src_sorted, eid_sorted,
                                              ea, We1, be1, B1);
    node_mfma<40><<<ngrid, blk, 0, stream>>>(x, B1, B1, W1, b1, g1, bb1, m1, v1);
    // layer 2
    agg_kernel<64><<<agrid, blk, 0, stream>>>(B1, 64, row_ptr, src_sorted, eid_sorted,
                                              ea, We2, be2, B2);
    node_mfma<64><<<ngrid, blk, 0, stream>>>(B1, B2, B2, W2, b2, g2, bb2, m2, v2);
    // layer 3
    agg_kernel<64><<<agrid, blk, 0, stream>>>(B2, 64, row_ptr, src_sorted, eid_sorted,
                                              ea, We3, be3, B3);
    node_mfma<64><<<ngrid, blk, 0, stream>>>(B2, B3, B3, W3, b3, g3, bb3, m3, v3);
    // pool
    pool_kernel<<<pgrid, blk, 0, stream>>>(B3, batch, hpool);
    // head (MFMA)
    head_kernel<<<hgrid, blk, 0, stream>>>(B1, B2, B3, hpool, batch,
                                           Wl1, bl1, Wl2, bl2, out);
}

// Round 7
// 656.770 us; speedup vs baseline: 1.9106x; 1.2430x over previous
//
#include <hip/hip_runtime.h>
#include <hip/hip_bf16.h>

#define N_NODES 200000
#define N_EDGES 800000
#define N_MOL   10000
#define HDIM    64
#define EDGE_DIM 16
#define BN_EPS 1e-5f
#define SCAN_BLOCKS ((N_NODES + 255) / 256)   // 782

typedef __attribute__((ext_vector_type(8))) short short8;
typedef __attribute__((ext_vector_type(4))) float f32x4;

// ---------------------------------------------------------------------------
// bf16 helpers
// ---------------------------------------------------------------------------
__device__ __forceinline__ unsigned int pk2(float a, float b) {
    __hip_bfloat162 h = __float22bfloat162_rn(make_float2(a, b));
    union { __hip_bfloat162 h; unsigned int u; } c;
    c.h = h;
    return c.u;
}
__device__ __forceinline__ short8 cvt8(float4 a, float4 b) {
    union { short8 s; unsigned int u[4]; } r;
    r.u[0] = pk2(a.x, a.y); r.u[1] = pk2(a.z, a.w);
    r.u[2] = pk2(b.x, b.y); r.u[3] = pk2(b.z, b.w);
    return r.s;
}
__device__ __forceinline__ float bf2f(unsigned short u) {
    return __uint_as_float(((unsigned int)u) << 16);
}

// ---------------------------------------------------------------------------
// x -> bf16 copy (layer-1 gather source)
// ---------------------------------------------------------------------------
__global__ __launch_bounds__(256) void cvtx_kernel(
    const float* __restrict__ x, unsigned short* __restrict__ xb)
{
    int i = blockIdx.x * 256 + threadIdx.x;
    if ((size_t)i * 4 >= (size_t)N_NODES * 40) return;
    float4 v = *(const float4*)(x + (size_t)i * 4);
    union { ushort4 s; unsigned int u[2]; } r;
    r.u[0] = pk2(v.x, v.y); r.u[1] = pk2(v.z, v.w);
    *(ushort4*)(xb + (size_t)i * 4) = r.s;
}

// ---------------------------------------------------------------------------
// CSR build: histogram -> 3-phase parallel scan -> scatter
// ---------------------------------------------------------------------------
__global__ __launch_bounds__(256) void hist_kernel(
    const int* __restrict__ ei, int* __restrict__ counts)
{
    int e = blockIdx.x * 256 + threadIdx.x;
    if (e < N_EDGES) atomicAdd(&counts[ei[N_EDGES + e]], 1);
}

__global__ __launch_bounds__(256) void scan_phase_a(
    const int* __restrict__ counts,
    int* __restrict__ row_ptr, int* __restrict__ block_sums)
{
    __shared__ int lds[256];
    int t = threadIdx.x;
    int i = blockIdx.x * 256 + t;
    int v = (i < N_NODES) ? counts[i] : 0;
    lds[t] = v;
    __syncthreads();
    for (int off = 1; off < 256; off <<= 1) {
        int u = (t >= off) ? lds[t - off] : 0;
        __syncthreads();
        lds[t] += u;
        __syncthreads();
    }
    if (i < N_NODES) row_ptr[i] = lds[t] - v;
    if (t == 255) block_sums[blockIdx.x] = lds[255];
}

__global__ __launch_bounds__(1024) void scan_phase_b(
    int* __restrict__ block_sums)
{
    __shared__ int lds[1024];
    int t = threadIdx.x;
    int v = (t < SCAN_BLOCKS) ? block_sums[t] : 0;
    lds[t] = v;
    __syncthreads();
    for (int off = 1; off < 1024; off <<= 1) {
        int u = (t >= off) ? lds[t - off] : 0;
        __syncthreads();
        lds[t] += u;
        __syncthreads();
    }
    if (t < SCAN_BLOCKS) block_sums[t] = lds[t] - v;
}

__global__ __launch_bounds__(256) void scan_phase_c(
    const int* __restrict__ block_sums,
    int* __restrict__ row_ptr, int* __restrict__ cursor)
{
    int i = blockIdx.x * 256 + threadIdx.x;
    if (i < N_NODES) {
        int v = row_ptr[i] + block_sums[blockIdx.x];
        row_ptr[i] = v;
        cursor[i] = v;
    }
    if (i == 0) row_ptr[N_NODES] = N_EDGES;
}

__global__ __launch_bounds__(256) void scatter_kernel(
    const int* __restrict__ ei, int* __restrict__ cursor,
    int* __restrict__ src_sorted, int* __restrict__ eid_sorted)
{
    int e = blockIdx.x * 256 + threadIdx.x;
    if (e >= N_EDGES) return;
    int d = ei[N_EDGES + e];
    int pos = atomicAdd(&cursor[d], 1);
    src_sorted[pos] = ei[e];
    eid_sorted[pos] = e;
}

// ---------------------------------------------------------------------------
// Gather-aggregate v2: wave owns 8 consecutive dst nodes. Edge ids are
// wave-uniform (readfirstlane) -> eid/src/ea all go through SGPR scalar
// loads; the 16-FMA edge MLP uses SGPR operands (no shfl, no DS). Feature
// gathers are bf16 rows. Output row = x_dst + sum(msg)  (dst-add fused).
// AGG cols >= DIN are written as exact zeros (MFMA K-padding downstream).
// ---------------------------------------------------------------------------
template<int DIN>
__global__ __launch_bounds__(256) void agg_kernel(
    const unsigned short* __restrict__ feat,  // [N, DIN] bf16
    const int*   __restrict__ row_ptr,
    const int*   __restrict__ src_sorted,
    const int*   __restrict__ eid_sorted,
    const float* __restrict__ ea,
    const float* __restrict__ We,     // [DIN, 16]
    const float* __restrict__ be,     // [DIN]
    float*       __restrict__ AGG)    // [N, 64] = x_dst + agg, fully written
{
    int lane = threadIdx.x & 63;
    int wv = __builtin_amdgcn_readfirstlane(blockIdx.x * 4 + (threadIdx.x >> 6));
    int n0 = wv * 8;
    if (n0 >= N_NODES) return;
    int f = lane;

    float wrow[16];
    float bias = 0.f;
    if (f < DIN) {
#pragma unroll
        for (int j = 0; j < 16; j++) wrow[j] = We[f * 16 + j];
        bias = be[f];
    } else {
#pragma unroll
        for (int j = 0; j < 16; j++) wrow[j] = 0.f;
    }

    int lo = row_ptr[n0];
    int hi = row_ptr[n0 + 8];
    int cur = 0;
    int nb = row_ptr[n0 + 1];
    float acc = 0.f;

    for (int j0 = lo; j0 < hi; j0 += 8) {
        int jn = min(8, hi - j0);             // wave-uniform
        int s[8], e[8];                       // SGPR (uniform), const-indexed
#pragma unroll
        for (int k = 0; k < 8; k++) {
            int j = min(j0 + k, hi - 1);
            s[k] = src_sorted[j];
            e[k] = eid_sorted[j];
        }
        float xv[8];                          // 8 gathers in flight
#pragma unroll
        for (int k = 0; k < 8; k++)
            xv[k] = (f < DIN) ? bf2f(feat[(size_t)s[k] * DIN + f]) : 0.f;

#pragma unroll
        for (int k = 0; k < 8; k++) {
            if (k >= jn) break;               // wave-uniform
            int j = j0 + k;
            while (j >= nb) {                 // flush node boundary
                float xd = (f < DIN) ? bf2f(feat[(size_t)(n0 + cur) * DIN + f]) : 0.f;
                AGG[(size_t)(n0 + cur) * HDIM + f] = acc + xd;
                acc = 0.f;
                cur++;
                nb = row_ptr[n0 + cur + 1];
            }
            const float4* ep = (const float4*)(ea + (size_t)e[k] * 16);
            float4 q0 = ep[0], q1 = ep[1], q2 = ep[2], q3 = ep[3];  // SGPR
            float a = bias;
            a = fmaf(q0.x, wrow[0],  a); a = fmaf(q0.y, wrow[1],  a);
            a = fmaf(q0.z, wrow[2],  a); a = fmaf(q0.w, wrow[3],  a);
            a = fmaf(q1.x, wrow[4],  a); a = fmaf(q1.y, wrow[5],  a);
            a = fmaf(q1.z, wrow[6],  a); a = fmaf(q1.w, wrow[7],  a);
            a = fmaf(q2.x, wrow[8],  a); a = fmaf(q2.y, wrow[9],  a);
            a = fmaf(q2.z, wrow[10], a); a = fmaf(q2.w, wrow[11], a);
            a = fmaf(q3.x, wrow[12], a); a = fmaf(q3.y, wrow[13], a);
            a = fmaf(q3.z, wrow[14], a); a = fmaf(q3.w, wrow[15], a);
            acc += fmaxf(xv[k] + a, 0.f);
        }
    }
    while (cur < 8) {
        float xd = (f < DIN) ? bf2f(feat[(size_t)(n0 + cur) * DIN + f]) : 0.f;
        AGG[(size_t)(n0 + cur) * HDIM + f] = acc + xd;
        acc = 0.f;
        cur++;
    }
}

// ---------------------------------------------------------------------------
// Node MFMA: Hb = bf16( leaky_relu(BN(AGG @ W.T + b)) )
// AGG already holds x+agg; cols >= DIN are zero (K padding).
// ---------------------------------------------------------------------------
template<int DIN>
__global__ __launch_bounds__(256) void node_mfma(
    const float*    __restrict__ AGG,   // [N, 64]
    unsigned short* __restrict__ Hb,    // [N, 64] bf16 out
    const float* __restrict__ W,        // [64, DIN]
    const float* __restrict__ bias,
    const float* __restrict__ gam,
    const float* __restrict__ bet,
    const float* __restrict__ mean,
    const float* __restrict__ var)
{
    int lane = threadIdx.x & 63;
    int wave = blockIdx.x * 4 + (threadIdx.x >> 6);
    if (wave >= N_NODES / 64) return;
    int n0 = wave * 64;
    int r = lane & 15;
    int g = lane >> 4;

    const short8 zero8 = (short8){0, 0, 0, 0, 0, 0, 0, 0};

    short8 zf[4][2];
#pragma unroll
    for (int nt = 0; nt < 4; nt++) {
        int node = n0 + nt * 16 + r;
        const float* ar = AGG + (size_t)node * HDIM;
        float4 a0 = *(const float4*)(ar + g * 8);
        float4 a1 = *(const float4*)(ar + g * 8 + 4);
        zf[nt][0] = cvt8(a0, a1);
        a0 = *(const float4*)(ar + 32 + g * 8);
        a1 = *(const float4*)(ar + 36 + g * 8);
        zf[nt][1] = cvt8(a0, a1);             // cols >= DIN are zero already
    }

    const float4* b4  = (const float4*)bias;
    const float4* g4  = (const float4*)gam;
    const float4* be4 = (const float4*)bet;
    const float4* m4  = (const float4*)mean;
    const float4* v4  = (const float4*)var;

#pragma unroll
    for (int ft = 0; ft < 4; ft++) {
        const float* wr = W + (size_t)(ft * 16 + r) * DIN;
        short8 af[2];
        {
            float4 w0 = *(const float4*)(wr + g * 8);
            float4 w1 = *(const float4*)(wr + g * 8 + 4);
            af[0] = cvt8(w0, w1);
            if (DIN == 64) {
                w0 = *(const float4*)(wr + 32 + g * 8);
                w1 = *(const float4*)(wr + 36 + g * 8);
                af[1] = cvt8(w0, w1);
            } else if (g == 0) {
                w0 = *(const float4*)(wr + 32);
                w1 = *(const float4*)(wr + 36);
                af[1] = cvt8(w0, w1);
            } else {
                af[1] = zero8;
            }
        }

        f32x4 acc[4];
#pragma unroll
        for (int nt = 0; nt < 4; nt++) acc[nt] = (f32x4){0.f, 0.f, 0.f, 0.f};

#pragma unroll
        for (int ks = 0; ks < 2; ks++) {
#pragma unroll
            for (int nt = 0; nt < 4; nt++) {
                acc[nt] = __builtin_amdgcn_mfma_f32_16x16x32_bf16(
                    af[ks], zf[nt][ks], acc[nt], 0, 0, 0);
            }
        }

        int idx = ft * 4 + g;
        float4 bb = b4[idx], gg = g4[idx], bt = be4[idx], mm = m4[idx], vv = v4[idx];
        float s0 = gg.x * rsqrtf(vv.x + BN_EPS);
        float s1 = gg.y * rsqrtf(vv.y + BN_EPS);
        float s2 = gg.z * rsqrtf(vv.z + BN_EPS);
        float s3 = gg.w * rsqrtf(vv.w + BN_EPS);
#pragma unroll
        for (int nt = 0; nt < 4; nt++) {
            int node = n0 + nt * 16 + r;
            float y0 = s0 * (acc[nt][0] + bb.x - mm.x) + bt.x;
            float y1 = s1 * (acc[nt][1] + bb.y - mm.y) + bt.y;
            float y2 = s2 * (acc[nt][2] + bb.z - mm.z) + bt.z;
            float y3 = s3 * (acc[nt][3] + bb.w - mm.w) + bt.w;
            y0 = (y0 > 0.f) ? y0 : 0.01f * y0;
            y1 = (y1 > 0.f) ? y1 : 0.01f * y1;
            y2 = (y2 > 0.f) ? y2 : 0.01f * y2;
            y3 = (y3 > 0.f) ? y3 : 0.01f * y3;
            union { uint2 v; unsigned int u[2]; } st;
            st.u[0] = pk2(y0, y1);
            st.u[1] = pk2(y2, y3);
            *(uint2*)(Hb + (size_t)node * HDIM + ft * 16 + g * 4) = st.v;
        }
    }
}

// ---------------------------------------------------------------------------
// Pool: hpool[batch[i]] += h3[i]  (bf16 in, f32 atomic accum)
// ---------------------------------------------------------------------------
__global__ __launch_bounds__(256) void pool_kernel(
    const unsigned short* __restrict__ h3b,
    const int*   __restrict__ batch,
    float*       __restrict__ hpool)
{
    int gid = blockIdx.x * 256 + threadIdx.x;
    if (gid >= N_NODES * HDIM) return;
    int i = gid >> 6, f = gid & 63;
    atomicAdd(&hpool[(size_t)batch[i] * HDIM + f], bf2f(h3b[gid]));
}

// ---------------------------------------------------------------------------
// Head: out[i] = Wl2 . leaky(Wl1 @ z_i + bl1) + bl2
// z_i = [h1|h2|h3|hpool[batch]]; h* read directly as bf16 fragments.
// ---------------------------------------------------------------------------
__global__ __launch_bounds__(256) void head_kernel(
    const unsigned short* __restrict__ h1b,
    const unsigned short* __restrict__ h2b,
    const unsigned short* __restrict__ h3b,
    const float* __restrict__ hpool,
    const int*   __restrict__ batch,
    const float* __restrict__ Wl1, const float* __restrict__ bl1,
    const float* __restrict__ Wl2, const float* __restrict__ bl2,
    float*       __restrict__ out)
{
    int lane = threadIdx.x & 63;
    int wave = blockIdx.x * 4 + (threadIdx.x >> 6);
    if (wave >= N_NODES / 64) return;
    int n0 = wave * 64;
    int r = lane & 15;
    int g = lane >> 4;

    short8 zf[4][8];
#pragma unroll
    for (int nt = 0; nt < 4; nt++) {
        int node = n0 + nt * 16 + r;
        const unsigned short* r1 = h1b + (size_t)node * 64;
        const unsigned short* r2 = h2b + (size_t)node * 64;
        const unsigned short* r3 = h3b + (size_t)node * 64;
        const float* rp = hpool + (size_t)batch[node] * 64;
        zf[nt][0] = *(const short8*)(r1 + g * 8);
        zf[nt][1] = *(const short8*)(r1 + 32 + g * 8);
        zf[nt][2] = *(const short8*)(r2 + g * 8);
        zf[nt][3] = *(const short8*)(r2 + 32 + g * 8);
        zf[nt][4] = *(const short8*)(r3 + g * 8);
        zf[nt][5] = *(const short8*)(r3 + 32 + g * 8);
        const float4* q;
        q = (const float4*)(rp + g * 8);        zf[nt][6] = cvt8(q[0], q[1]);
        q = (const float4*)(rp + 32 + g * 8);   zf[nt][7] = cvt8(q[0], q[1]);
    }

    float p[4] = {0.f, 0.f, 0.f, 0.f};

    const float4* bl1_4 = (const float4*)bl1;
    const float4* wl2_4 = (const float4*)Wl2;

#pragma unroll 1
    for (int ft = 0; ft < 16; ft++) {
        const float* arow = Wl1 + (size_t)(ft * 16 + r) * 256 + g * 8;
        short8 af[8];
#pragma unroll
        for (int ks = 0; ks < 8; ks++) {
            const float4* q = (const float4*)(arow + ks * 32);
            af[ks] = cvt8(q[0], q[1]);
        }

        f32x4 acc[4];
#pragma unroll
        for (int nt = 0; nt < 4; nt++) acc[nt] = (f32x4){0.f, 0.f, 0.f, 0.f};

#pragma unroll
        for (int ks = 0; ks < 8; ks++) {
#pragma unroll
            for (int nt = 0; nt < 4; nt++) {
                acc[nt] = __builtin_amdgcn_mfma_f32_16x16x32_bf16(
                    af[ks], zf[nt][ks], acc[nt], 0, 0, 0);
            }
        }

        float4 bl = bl1_4[ft * 4 + g];
        float4 w2 = wl2_4[ft * 4 + g];
#pragma unroll
        for (int nt = 0; nt < 4; nt++) {
            float a0 = acc[nt][0] + bl.x;
            float a1 = acc[nt][1] + bl.y;
            float a2 = acc[nt][2] + bl.z;
            float a3 = acc[nt][3] + bl.w;
            a0 = (a0 > 0.f) ? a0 : 0.01f * a0;
            a1 = (a1 > 0.f) ? a1 : 0.01f * a1;
            a2 = (a2 > 0.f) ? a2 : 0.01f * a2;
            a3 = (a3 > 0.f) ? a3 : 0.01f * a3;
            p[nt] += w2.x * a0 + w2.y * a1 + w2.z * a2 + w2.w * a3;
        }
    }

    float b2 = bl2[0];
#pragma unroll
    for (int nt = 0; nt < 4; nt++) {
        float s = p[nt];
        s += __shfl_xor(s, 16, 64);
        s += __shfl_xor(s, 32, 64);
        if (g == 0) out[n0 + nt * 16 + r] = s + b2;
    }
}

// ---------------------------------------------------------------------------
extern "C" void kernel_launch(void* const* d_in, const int* in_sizes, int n_in,
                              void* d_out, int out_size, void* d_ws, size_t ws_size,
                              hipStream_t stream) {
    const float* x     = (const float*)d_in[0];
    const int*   ei    = (const int*)  d_in[1];
    const float* ea    = (const float*)d_in[2];
    const int*   batch = (const int*)  d_in[3];

    const float* We1 = (const float*)d_in[4];  const float* be1 = (const float*)d_in[5];
    const float* W1  = (const float*)d_in[6];  const float* b1  = (const float*)d_in[7];
    const float* g1  = (const float*)d_in[8];  const float* bb1 = (const float*)d_in[9];
    const float* m1  = (const float*)d_in[10]; const float* v1  = (const float*)d_in[11];

    const float* We2 = (const float*)d_in[12]; const float* be2 = (const float*)d_in[13];
    const float* W2  = (const float*)d_in[14]; const float* b2  = (const float*)d_in[15];
    const float* g2  = (const float*)d_in[16]; const float* bb2 = (const float*)d_in[17];
    const float* m2  = (const float*)d_in[18]; const float* v2  = (const float*)d_in[19];

    const float* We3 = (const float*)d_in[20]; const float* be3 = (const float*)d_in[21];
    const float* W3  = (const float*)d_in[22]; const float* b3  = (const float*)d_in[23];
    const float* g3  = (const float*)d_in[24]; const float* bb3 = (const float*)d_in[25];
    const float* m3  = (const float*)d_in[26]; const float* v3  = (const float*)d_in[27];

    const float* Wl1 = (const float*)d_in[28]; const float* bl1 = (const float*)d_in[29];
    const float* Wl2 = (const float*)d_in[30]; const float* bl2 = (const float*)d_in[31];

    float* out = (float*)d_out;

    // ---- workspace layout (~155 MB) ----
    float* AGG            = (float*)d_ws;                        // [N,64] f32
    unsigned short* xb    = (unsigned short*)(AGG + (size_t)N_NODES * HDIM); // [N,40]
    unsigned short* Hb1   = xb + (size_t)N_NODES * 40;           // [N,64] bf16
    unsigned short* Hb2   = Hb1 + (size_t)N_NODES * HDIM;
    unsigned short* Hb3   = Hb2 + (size_t)N_NODES * HDIM;
    float* hpool          = (float*)(Hb3 + (size_t)N_NODES * HDIM); // [N_MOL,64]
    int* counts     = (int*)(hpool + (size_t)N_MOL * HDIM);      // [N]
    int* row_ptr    = counts + N_NODES;                          // [N+1]
    int* cursor     = row_ptr + N_NODES + 1;                     // [N]
    int* src_sorted = cursor + N_NODES;                          // [E]
    int* eid_sorted = src_sorted + N_EDGES;                      // [E]
    int* block_sums = eid_sorted + N_EDGES;                      // [SCAN_BLOCKS]

    hipMemsetAsync(hpool, 0, (size_t)N_MOL * HDIM * sizeof(float), stream);
    hipMemsetAsync(counts, 0, (size_t)N_NODES * sizeof(int), stream);

    dim3 blk(256);
    dim3 cgrid(((size_t)N_NODES * 40 / 4 + 255) / 256);
    dim3 egrid(N_EDGES / 256);
    dim3 sgrid(SCAN_BLOCKS);
    dim3 agrid((N_NODES / 8) / 4);
    dim3 ngrid((N_NODES / 64 + 3) / 4);
    dim3 pgrid((N_NODES * HDIM) / 256);
    dim3 hgrid((N_NODES / 64 + 3) / 4);

    // ---- prep ----
    cvtx_kernel<<<cgrid, blk, 0, stream>>>(x, xb);
    hist_kernel<<<egrid, blk, 0, stream>>>(ei, counts);
    scan_phase_a<<<sgrid, blk, 0, stream>>>(counts, row_ptr, block_sums);
    scan_phase_b<<<1, 1024, 0, stream>>>(block_sums);
    scan_phase_c<<<sgrid, blk, 0, stream>>>(block_sums, row_ptr, cursor);
    scatter_kernel<<<egrid, blk, 0, stream>>>(ei, cursor, src_sorted, eid_sorted);

    // layer 1
    agg_kernel<40><<<agrid, blk, 0, stream>>>(xb, row_ptr, src_sorted, eid_sorted,
                                              ea, We1, be1, AGG);
    node_mfma<40><<<ngrid, blk, 0, stream>>>(AGG, Hb1, W1, b1, g1, bb1, m1, v1);
    // layer 2
    agg_kernel<64><<<agrid, blk, 0, stream>>>(Hb1, row_ptr, src_sorted, eid_sorted,
                                              ea, We2, be2, AGG);
    node_mfma<64><<<ngrid, blk, 0, stream>>>(AGG, Hb2, W2, b2, g2, bb2, m2, v2);
    // layer 3
    agg_kernel<64><<<agrid, blk, 0, stream>>>(Hb2, row_ptr, src_sorted, eid_sorted,
                                              ea, We3, be3, AGG);
    node_mfma<64><<<ngrid, blk, 0, stream>>>(AGG, Hb3, W3, b3, g3, bb3, m3, v3);
    // pool
    pool_kernel<<<pgrid, blk, 0, stream>>>(Hb3, batch, hpool);
    // head
    head_kernel<<<hgrid, blk, 0, stream>>>(Hb1, Hb2, Hb3, hpool, batch,
                                           Wl1, bl1, Wl2, bl2, out);
}